// Round 4
// baseline (168.407 us; speedup 1.0000x reference)
//
#include <hip/hip_runtime.h>

// LoRA linear, fp32 in/out: out = x @ (W + 2*B@A)^T + b
//   prep: Weff = bf16(W + 2*B@A) (2 MiB ws)  +  xbf = bf16(x) (32 MiB ws)
//   gemm: 128x128x32 bf16 MFMA (16x16x32), global_load_lds w=16,
//         XOR k-chunk swizzle (0 bank conflicts, verified R3),
//         DOUBLE-BUFFERED LDS: prefetch tile k+1 during compute of tile k,
//         single barrier per iteration (R3 had 2 + zero-overlap drain).

typedef __bf16 bf16x8 __attribute__((ext_vector_type(8)));
typedef float f32x4 __attribute__((ext_vector_type(4)));
typedef unsigned short ushort8 __attribute__((ext_vector_type(8)));  // 16B

__device__ __forceinline__ unsigned short f2bf(float f) {
    union { __bf16 b; unsigned short u; } v; v.b = (__bf16)f; return v.u;
}
__device__ __forceinline__ ushort8 cvt8(f32x4 a, f32x4 b) {
    ushort8 o;
#pragma unroll
    for (int i = 0; i < 4; ++i) { o[i] = f2bf(a[i]); o[i + 4] = f2bf(b[i]); }
    return o;
}
__device__ __forceinline__ void gld16(const unsigned short* g, unsigned short* l) {
    __builtin_amdgcn_global_load_lds(
        (const __attribute__((address_space(1))) unsigned int*)g,
        (__attribute__((address_space(3))) unsigned int*)l, 16, 0, 0);
}

// ---------------- prep ----------------
__global__ __launch_bounds__(256) void prep(
    const float* __restrict__ X, const float* __restrict__ W,
    const float* __restrict__ A, const float* __restrict__ B,
    unsigned short* __restrict__ xbf, unsigned short* __restrict__ Weff)
{
    const int b = blockIdx.x;
    if (b < 512) {
        const int idx = b * 256 + threadIdx.x;
        const int o  = idx >> 7;
        const int kc = (idx & 127) << 3;
        float br[16];
#pragma unroll
        for (int r = 0; r < 16; ++r) br[r] = 2.0f * B[o * 16 + r];
        float acc[8];
        const float* wrow = W + (size_t)o * 1024 + kc;
#pragma unroll
        for (int j = 0; j < 8; ++j) acc[j] = wrow[j];
#pragma unroll
        for (int r = 0; r < 16; ++r) {
            const float* arow = A + r * 1024 + kc;
#pragma unroll
            for (int j = 0; j < 8; ++j) acc[j] += br[r] * arow[j];
        }
        ushort8 o8;
#pragma unroll
        for (int j = 0; j < 8; ++j) o8[j] = f2bf(acc[j]);
        *(ushort8*)(Weff + (size_t)o * 1024 + kc) = o8;
    } else {
        const size_t i = ((size_t)(b - 512) * 256 + threadIdx.x) * 8;
        f32x4 a = *(const f32x4*)(X + i);
        f32x4 c = *(const f32x4*)(X + i + 4);
        *(ushort8*)(xbf + i) = cvt8(a, c);
    }
}

// ---------------- gemm ----------------
// 256 thr = 4 waves, each wave one 64x64 quadrant (4x4 of 16x16x32 MFMA).
// LDS: 2 x (A 8KB + B 8KB) = 32 KB. Lane-contiguous layout (gld16 constraint);
// k-chunk position XOR-swizzled by (row>>1)&3 on the GLOBAL source address.
template <bool XF32>
__global__ __launch_bounds__(256) void gemm_bt(
    const void* __restrict__ X_,               // bf16 [M][1024] (fp32 in fallback)
    const unsigned short* __restrict__ Wt,     // bf16 Weff [1024][1024]
    const float* __restrict__ bias,            // fp32 [1024]
    float* __restrict__ out)                   // fp32 [M][1024]
{
    __shared__ __align__(16) unsigned short lA0[128 * 32];
    __shared__ __align__(16) unsigned short lA1[128 * 32];
    __shared__ __align__(16) unsigned short lB0[128 * 32];
    __shared__ __align__(16) unsigned short lB1[128 * 32];

    const int t    = threadIdx.x;
    const int lane = t & 63;
    const int w    = t >> 6;
    const int bm   = blockIdx.x * 128;
    const int bn   = blockIdx.y * 128;
    const int wm   = (w & 1) * 64;
    const int wn   = (w >> 1) * 64;
    const int r16  = lane & 15;
    const int quad = lane >> 4;

    // staging map: thread t -> LDS offset t*16B; global k-chunk swizzled
    const int srow = t >> 2;                       // 0..63 (+64 on 2nd load)
    const int gc   = (t & 3) ^ ((srow >> 1) & 3);
    const size_t ga0 = (size_t)(bm + srow) * 1024 + gc * 8;
    const size_t ga1 = (size_t)(bm + srow + 64) * 1024 + gc * 8;
    const unsigned short* gB0 = Wt + (size_t)(bn + srow) * 1024 + gc * 8;

    // reader un-swizzle
    const int p    = (quad ^ ((r16 >> 1) & 3)) * 8;
    const int aoff = (wm + r16) * 32 + p;
    const int boff = (wn + r16) * 32 + p;

    const unsigned short* Xb = (const unsigned short*)X_;
    const float*          Xf = (const float*)X_;

    f32x4 acc[4][4];
#pragma unroll
    for (int i = 0; i < 4; ++i)
#pragma unroll
        for (int j = 0; j < 4; ++j) {
            f32x4 z = {0.f, 0.f, 0.f, 0.f};
            acc[i][j] = z;
        }

    unsigned short* sA  = lA0;  unsigned short* sAn = lA1;
    unsigned short* sB  = lB0;  unsigned short* sBn = lB1;

    // prologue: stage tile 0 into buf0
    if (XF32) {
        f32x4 a0 = *(const f32x4*)(Xf + ga0);
        f32x4 a1 = *(const f32x4*)(Xf + ga0 + 4);
        f32x4 a2 = *(const f32x4*)(Xf + ga1);
        f32x4 a3 = *(const f32x4*)(Xf + ga1 + 4);
        *(ushort8*)(sA + t * 8)        = cvt8(a0, a1);
        *(ushort8*)(sA + 2048 + t * 8) = cvt8(a2, a3);
    } else {
        gld16(Xb + ga0, sA + t * 8);
        gld16(Xb + ga1, sA + 2048 + t * 8);
    }
    gld16(gB0,             sB + t * 8);
    gld16(gB0 + 64 * 1024, sB + 2048 + t * 8);
    __syncthreads();

    for (int kt = 0; kt < 1024; kt += 32) {
        // prefetch tile kt+32 into the idle buffers (overlaps with compute below)
        if (kt + 32 < 1024) {
            const int kn = kt + 32;
            if (XF32) {
                f32x4 a0 = *(const f32x4*)(Xf + ga0 + kn);
                f32x4 a1 = *(const f32x4*)(Xf + ga0 + kn + 4);
                f32x4 a2 = *(const f32x4*)(Xf + ga1 + kn);
                f32x4 a3 = *(const f32x4*)(Xf + ga1 + kn + 4);
                *(ushort8*)(sAn + t * 8)        = cvt8(a0, a1);
                *(ushort8*)(sAn + 2048 + t * 8) = cvt8(a2, a3);
            } else {
                gld16(Xb + ga0 + kn, sAn + t * 8);
                gld16(Xb + ga1 + kn, sAn + 2048 + t * 8);
            }
            gld16(gB0 + kn,             sBn + t * 8);
            gld16(gB0 + kn + 64 * 1024, sBn + 2048 + t * 8);
        }

        bf16x8 fa[4], fb[4];
#pragma unroll
        for (int mt = 0; mt < 4; ++mt) fa[mt] = *(const bf16x8*)(sA + aoff + mt * 16 * 32);
#pragma unroll
        for (int nt = 0; nt < 4; ++nt) fb[nt] = *(const bf16x8*)(sB + boff + nt * 16 * 32);

#pragma unroll
        for (int mt = 0; mt < 4; ++mt)
#pragma unroll
            for (int nt = 0; nt < 4; ++nt)
                acc[mt][nt] = __builtin_amdgcn_mfma_f32_16x16x32_bf16(
                    fa[mt], fb[nt], acc[mt][nt], 0, 0, 0);

        // swap buffers; single barrier: drains prefetch + protects cur from overwrite
        unsigned short* tp;
        tp = sA; sA = sAn; sAn = tp;
        tp = sB; sB = sBn; sBn = tp;
        __syncthreads();
    }

    // epilogue: C/D layout col=lane&15, row=quad*4+reg (verified end-to-end R2/R3)
    const int orow0 = bm + wm + quad * 4;
    const int ocol0 = bn + wn + r16;
#pragma unroll
    for (int nt = 0; nt < 4; ++nt) {
        const float bv = bias[ocol0 + nt * 16];
#pragma unroll
        for (int mt = 0; mt < 4; ++mt)
#pragma unroll
            for (int i = 0; i < 4; ++i)
                out[(size_t)(orow0 + mt * 16 + i) * 1024 + (ocol0 + nt * 16)] =
                    acc[mt][nt][i] + bv;
    }
}

extern "C" void kernel_launch(void* const* d_in, const int* in_sizes, int n_in,
                              void* d_out, int out_size, void* d_ws, size_t ws_size,
                              hipStream_t stream) {
    const float* x  = (const float*)d_in[0];   // [M][1024]
    const float* W  = (const float*)d_in[1];   // [1024][1024]
    const float* b  = (const float*)d_in[2];   // [1024]
    const float* A  = (const float*)d_in[3];   // [16][1024]
    const float* Bm = (const float*)d_in[4];   // [1024][16]
    float* out = (float*)d_out;

    const int M = in_sizes[0] / 1024;          // 16384
    dim3 grid(M / 128, 1024 / 128);

    const bool fast = ws_size >= ((size_t)(M)*1024*2 + (2u << 20) + 4096);
    if (fast) {
        unsigned short* xbf  = (unsigned short*)d_ws;
        unsigned short* Weff = xbf + (size_t)M * 1024;
        hipLaunchKernelGGL(prep, dim3(512 + M / 2), dim3(256), 0, stream,
                           x, W, A, Bm, xbf, Weff);
        hipLaunchKernelGGL((gemm_bt<false>), grid, dim3(256), 0, stream,
                           (const void*)xbf, Weff, b, out);
    } else {
        unsigned short* Weff = (unsigned short*)d_ws;
        hipLaunchKernelGGL(prep, dim3(512), dim3(256), 0, stream,
                           x, W, A, Bm, (unsigned short*)nullptr, Weff);
        hipLaunchKernelGGL((gemm_bt<true>), grid, dim3(256), 0, stream,
                           (const void*)x, Weff, b, out);
    }
}